// Round 10
// baseline (22229.138 us; speedup 1.0000x reference)
//
#include <hip/hip_runtime.h>

// ---------------- problem constants ----------------
#define Tn   512
#define NWG  256
#define NTH  1024

// ---------------- ws layout (float words) ----------------
#define OFF_WCOMB 0                      // [2048][256]
#define OFF_BC0   524288                 // [2048]
#define OFF_EMBG  526336                 // [11][2048]
#define OFF_H0T   548864                 // [2][512*64] k-major (zero region start)
#define OFF_H1T   (OFF_H0T + 65536)      // [2][512*64]
#define OFF_C0T   (OFF_H1T + 65536)      // [512*64]
#define OFF_C1T   (OFF_C0T + 32768)
#define OFF_BAR   (OFF_C1T + 32768)      // done flag (32 words)
#define OFF_ARR   (OFF_BAR + 32)         // 256 arrival slots * 32
#define OFF_TAG1  (OFF_ARR + 8192)       // 256 head tags * 32
#define OFF_PTAG  (OFF_TAG1 + 8192)      // 64 prev tags * 32
#define ZERO_END  (OFF_PTAG + 2048)
#define ZERO_WORDS (ZERO_END - OFF_H0T)
#define OFF_PBUF  ZERO_END               // [704][64] floats used (region larger)
#define WS_WORDS  (OFF_PBUF + 704 * 256)

// out layout: logits [64][512][11] = 360448, zeros 360448, attn 32768
#define OUT_LOGITS_WORDS 360448
#define OUT_TAIL_WORDS   393216

// ---------------- setup kernels ----------------
__global__ void k_wcomb(const float* __restrict__ Wih0, const float* __restrict__ Wp,
                        const float* __restrict__ bp, const float* __restrict__ bih0,
                        const float* __restrict__ bhh0, float* __restrict__ ws) {
    int j = blockIdx.x;            // 0..2047
    int k = threadIdx.x;           // 0..255
    const float* row = Wih0 + (long)j * 1024;
    float acc = 0.f;
    for (int h = 0; h < 512; ++h) acc = fmaf(row[h], Wp[h * 256 + k], acc);
    ws[OFF_WCOMB + j * 256 + k] = acc;
    __shared__ float s[256];
    s[k] = row[k] * bp[k] + row[256 + k] * bp[256 + k];
    __syncthreads();
    for (int st = 128; st > 0; st >>= 1) { if (k < st) s[k] += s[k + st]; __syncthreads(); }
    if (k == 0) ws[OFF_BC0 + j] = bih0[j] + bhh0[j] + s[0];
}

__global__ void k_embg(const float* __restrict__ emb, const float* __restrict__ Wih0,
                       float* __restrict__ ws) {
    int cls = blockIdx.x >> 3;
    int j = ((blockIdx.x & 7) << 8) + threadIdx.x;
    const float* er = emb + cls * 512;
    const float* wr = Wih0 + (long)j * 1024 + 512;
    float acc = 0.f;
    for (int h = 0; h < 512; ++h) acc = fmaf(er[h], wr[h], acc);
    ws[OFF_EMBG + cls * 2048 + j] = acc;
}

// zero state + tags/barrier (MUST run every launch: graph replays reuse ws)
__global__ void k_zero(float* __restrict__ ws) {
    long i = (long)blockIdx.x * blockDim.x + threadIdx.x;
    if (i < ZERO_WORDS) ws[OFF_H0T + i] = 0.f;
}

// ---------------- main persistent kernel ----------------
struct MP {
    const float *mainf, *phys, *Whh0, *Wih1, *Whh1, *bih1, *bhh1, *W1, *b1, *W2, *b2;
    float* ws;
    float* out;
};

struct Seg {
    const float* act;   // base (batch offset applied inside)
    long rs;            // row stride for b-major
    int kmaj;           // 1: act[k*64+b]  0: act[b*rs+k]
    int klen;
    const float* wgt;   // weight base, row-major
    int wld;
    int wcol0;
    int coh;            // 1: coherent sc0/sc1 staging (cross-XCD data)
};

__device__ __forceinline__ float sigm(float x) { return 1.f / (1.f + expf(-x)); }

__device__ __forceinline__ void coh_issue16(const float* p, float4& v) {
    asm volatile("global_load_dwordx4 %0, %1, off sc0 sc1" : "=&v"(v) : "v"(p));
}
__device__ __forceinline__ void vm_wait0() {
    asm volatile("s_waitcnt vmcnt(0)" ::: "memory");
}
__device__ __forceinline__ void coh_store(float* p, float v) {
    __hip_atomic_store(p, v, __ATOMIC_RELAXED, __HIP_MEMORY_SCOPE_AGENT);
}

// CHUNK = 128 k-rows per staged tile.
__device__ __forceinline__ void resolve(int ch, int nch0, const Seg* sg, int& s, int& k0, int& kc) {
    if (ch < nch0) { s = 0; k0 = ch << 7; }
    else           { s = 1; k0 = (ch - nch0) << 7; }
    kc = sg[s].klen - k0; if (kc > 128) kc = 128;
}

// rows rg*NRH+jr, batch-float4 b4 (batches 4b4..4b4+3 of the WG's 16), k-slice q.
template <int NRH>
__device__ __forceinline__ void comp_tile(const float (*at)[20], const float (*wv)[132],
                                          int rg, int q, int b4, float* acc) {
    float4 a0 = *(const float4*)&at[4 * q + 0][b4 << 2];
    float4 a1 = *(const float4*)&at[4 * q + 1][b4 << 2];
    float4 a2 = *(const float4*)&at[4 * q + 2][b4 << 2];
    float4 a3 = *(const float4*)&at[4 * q + 3][b4 << 2];
    #pragma unroll
    for (int jr = 0; jr < NRH; ++jr) {
        float4 w4 = *(const float4*)&wv[rg * NRH + jr][q << 2];
        acc[jr * 4 + 0] = fmaf(w4.x, a0.x, acc[jr * 4 + 0]);
        acc[jr * 4 + 0] = fmaf(w4.y, a1.x, acc[jr * 4 + 0]);
        acc[jr * 4 + 0] = fmaf(w4.z, a2.x, acc[jr * 4 + 0]);
        acc[jr * 4 + 0] = fmaf(w4.w, a3.x, acc[jr * 4 + 0]);
        acc[jr * 4 + 1] = fmaf(w4.x, a0.y, acc[jr * 4 + 1]);
        acc[jr * 4 + 1] = fmaf(w4.y, a1.y, acc[jr * 4 + 1]);
        acc[jr * 4 + 1] = fmaf(w4.z, a2.y, acc[jr * 4 + 1]);
        acc[jr * 4 + 1] = fmaf(w4.w, a3.y, acc[jr * 4 + 1]);
        acc[jr * 4 + 2] = fmaf(w4.x, a0.z, acc[jr * 4 + 2]);
        acc[jr * 4 + 2] = fmaf(w4.y, a1.z, acc[jr * 4 + 2]);
        acc[jr * 4 + 2] = fmaf(w4.z, a2.z, acc[jr * 4 + 2]);
        acc[jr * 4 + 2] = fmaf(w4.w, a3.z, acc[jr * 4 + 2]);
        acc[jr * 4 + 3] = fmaf(w4.x, a0.w, acc[jr * 4 + 3]);
        acc[jr * 4 + 3] = fmaf(w4.y, a1.w, acc[jr * 4 + 3]);
        acc[jr * 4 + 3] = fmaf(w4.z, a2.w, acc[jr * 4 + 3]);
        acc[jr * 4 + 3] = fmaf(w4.w, a3.w, acc[jr * 4 + 3]);
    }
}

// Computes, for this WG's 16 batches (bq*16..+15) and NR rows
// j(r) = (r>>3)*jstride + j0 + (r&7), the dots over both segments.
// Results land in redf[r*17 + bb] (r<NR, bb<16). Hazard skeleton = r8/r9-proven.
template <int NR, int NRH>
__device__ void mm_run(const Seg* sg, int j0, int jstride, int bq, int tid,
                       float (*actA)[20], float (*actB)[20],
                       float (*wA)[132], float (*wB)[132],
                       float* redw, float* redf) {
    constexpr int NA = NRH * 4;
    const int b4 = tid & 3;
    const int q  = (tid >> 2) & 31;
    const int rg = tid >> 7;
    const int nch0 = (sg[0].klen + 127) >> 7;
    const int nch  = nch0 + ((sg[1].klen + 127) >> 7);
    const int nq0  = (nch + 1) >> 1;
    float acc[NA];
    #pragma unroll
    for (int i = 0; i < NA; ++i) acc[i] = 0.f;

    for (int it = 0; it < nq0; ++it) {
        const int chA = it, chB = nq0 + it;
        const bool hasB = chB < nch;
        int sA, kA, kcA; resolve(chA, nch0, sg, sA, kA, kcA);
        int sB = 0, kB = 0, kcB = 0;
        if (hasB) resolve(chB, nch0, sg, sB, kB, kcB);
        const Seg gA = sg[sA];
        const Seg gB = sg[sB];

        // ---- act staging: threads 0..511 stage buffer A, 512..1023 buffer B ----
        const int abuf = tid >> 9;           // wave-uniform
        const int st   = tid & 511;
        const Seg* gS  = abuf ? &gB : &gA;
        const int  kS  = abuf ? kB : kA;
        const int  kcS = abuf ? kcB : kcA;
        const bool bufOK = abuf ? hasB : true;
        float4 av;
        bool fAct = false;
        if (bufOK) {
            if (gS->kmaj) {
                int kk = st >> 2, b4f = st & 3;
                if (kk < kcS) {
                    const float* pp = gS->act + ((long)(kS + kk) << 6) + (bq << 4) + (b4f << 2);
                    fAct = true;
                    if (gS->coh) coh_issue16(pp, av); else av = *(const float4*)pp;
                }
            } else {
                int k4 = st >> 4, bb = st & 15;
                if ((k4 << 2) < kcS) {
                    const float* pp = gS->act + (long)(bq * 16 + bb) * gS->rs + kS + (k4 << 2);
                    fAct = true;
                    if (gS->coh) coh_issue16(pp, av); else av = *(const float4*)pp;
                }
            }
        }
        // ---- weight staging: all threads, float4; rw = tid>>5 row, kq = tid&31 ----
        float4 wva, wvb;
        bool fWA = false, fWB = false;
        const int rw = tid >> 5, kq = tid & 31;
        if (rw < NR) {
            int j = (rw >> 3) * jstride + j0 + (rw & 7);
            if ((kq << 2) < kcA) {
                wva = *(const float4*)(gA.wgt + (long)j * gA.wld + gA.wcol0 + kA + (kq << 2));
                fWA = true;
            }
            if (hasB && (kq << 2) < kcB) {
                wvb = *(const float4*)(gB.wgt + (long)j * gB.wld + gB.wcol0 + kB + (kq << 2));
                fWB = true;
            }
        }
        vm_wait0();
        // ---- LDS writes ----
        if (fAct) {
            float (*dst)[20] = abuf ? actB : actA;
            if (gS->kmaj) {
                int kk = st >> 2, b4f = st & 3;
                *(float4*)&dst[kk][b4f << 2] = av;
            } else {
                int k4 = st >> 4, bb = st & 15;
                dst[(k4 << 2) + 0][bb] = av.x; dst[(k4 << 2) + 1][bb] = av.y;
                dst[(k4 << 2) + 2][bb] = av.z; dst[(k4 << 2) + 3][bb] = av.w;
            }
        }
        if (fWA) *(float4*)&wA[rw][kq << 2] = wva;
        if (fWB) *(float4*)&wB[rw][kq << 2] = wvb;
        __syncthreads();
        // ---- compute ----
        if (4 * q < kcA) comp_tile<NRH>(actA, wA, rg, q, b4, acc);
        if (hasB && 4 * q < kcB) comp_tile<NRH>(actB, wB, rg, q, b4, acc);
        __syncthreads();
    }
    // ---- reduce 32 q-slices: 16 in-wave (lane bits 2..5), 2 across wave-pairs ----
    #pragma unroll
    for (int i = 0; i < NA; ++i) {
        acc[i] += __shfl_xor(acc[i], 4);
        acc[i] += __shfl_xor(acc[i], 8);
        acc[i] += __shfl_xor(acc[i], 16);
        acc[i] += __shfl_xor(acc[i], 32);
    }
    const int wv5 = tid >> 6, lane = tid & 63;
    const int q4 = wv5 & 1, rgw = wv5 >> 1;
    if (q4 == 1 && lane < 4) {
        const int base = (rgw * 4 + lane) * 17;
        #pragma unroll
        for (int i = 0; i < NA; ++i) redw[base + i] = acc[i];
    }
    __syncthreads();
    if (q4 == 0 && lane < 4) {
        const int base = (rgw * 4 + lane) * 17;
        #pragma unroll
        for (int i = 0; i < NA; ++i) acc[i] += redw[base + i];
        #pragma unroll
        for (int jr = 0; jr < NRH; ++jr)
            #pragma unroll
            for (int jb = 0; jb < 4; ++jb)
                redf[(rgw * NRH + jr) * 17 + lane * 4 + jb] = acc[jr * 4 + jb];
    }
    __syncthreads();
}

// Hierarchical barrier (r6-proven, stable).
__device__ __forceinline__ void gsync(int* done, int* arr, int w, int gen) {
    vm_wait0();
    __syncthreads();
    const int tid = threadIdx.x;
    if (tid == 0)
        __hip_atomic_store(&arr[w * 32], gen, __ATOMIC_RELAXED, __HIP_MEMORY_SCOPE_AGENT);
    if (w == 0) {
        if (tid < NWG) {
            int v;
            do {
                __builtin_amdgcn_s_sleep(1);
                v = __hip_atomic_load(&arr[tid * 32], __ATOMIC_RELAXED, __HIP_MEMORY_SCOPE_AGENT);
            } while (v < gen);
        }
        __syncthreads();
        if (tid == 0)
            __hip_atomic_store(done, gen, __ATOMIC_RELAXED, __HIP_MEMORY_SCOPE_AGENT);
    } else {
        if (tid == 0) {
            int v;
            do {
                __builtin_amdgcn_s_sleep(2);
                v = __hip_atomic_load(done, __ATOMIC_RELAXED, __HIP_MEMORY_SCOPE_AGENT);
            } while (v < gen);
        }
    }
    __syncthreads();
}

__global__ void __launch_bounds__(NTH, 4) k_main(MP p) {
    float* ws = p.ws;
    const float* Wcomb = ws + OFF_WCOMB;
    const float* bc0v  = ws + OFF_BC0;
    const float* embg  = ws + OFF_EMBG;
    float* h0T = ws + OFF_H0T;
    float* h1T = ws + OFF_H1T;
    float* c0T = ws + OFF_C0T;
    float* c1T = ws + OFF_C1T;
    float* pbuf = ws + OFF_PBUF;            // [704][64] used
    int* done = (int*)(ws + OFF_BAR);
    int* arr  = (int*)(ws + OFF_ARR);
    int* tag1 = (int*)(ws + OFF_TAG1);
    int* ptag = (int*)(ws + OFF_PTAG);

    __shared__ float actA[128][20], actB[128][20];   // 20.5 KB
    __shared__ float wA[32][132], wB[32][132];       // 33.8 KB
    __shared__ float redw[8 * 4 * 17];               //  2.2 KB
    __shared__ float redf[32 * 17];                  //  2.2 KB
    __shared__ float rrowS[8][17];
    __shared__ float slog[11];
    __shared__ int prevlS[16];

    const int w = blockIdx.x, tid = threadIdx.x;
    const int kg = w >> 2, bq = w & 3;               // 64 k-groups x 4 batch-quarters
    int gen = 0;

    for (int t = 0; t <= Tn; ++t) {
        const int cur = t & 1, prv = cur ^ 1;

        // ---------- head for step t-1: 8 W1-rows (kg*8..+7) x 16 batches ----------
        if (t >= 1) {
            Seg sg[2];
            sg[0] = { h1T + prv * 32768, 0, 1, 512, p.W1, 544, 0, 1 };
            sg[1] = { p.phys + (long)(t - 1) * 32, (long)Tn * 32, 0, 32, p.W1, 544, 512, 0 };
            mm_run<8, 1>(sg, kg * 8, 0, bq, tid, actA, actB, wA, wB, redw, redf);
            if (tid < 128) {
                int rr = tid >> 4, bb = tid & 15;
                float hv = redf[rr * 17 + bb] + p.b1[kg * 8 + rr];
                rrowS[rr][bb] = hv > 0.f ? hv : 0.f;
            }
            __syncthreads();
            if (tid < 176) {
                int bb = tid / 11, cc = tid - bb * 11;
                float s = 0.f;
                #pragma unroll
                for (int r = 0; r < 8; ++r)
                    s = fmaf(rrowS[r][bb], p.W2[cc * 512 + kg * 8 + r], s);
                int b = bq * 16 + bb;
                coh_store(&pbuf[(long)(b * 11 + cc) * 64 + kg], s);
            }
            vm_wait0();              // every wave drains its own pbuf stores
            __syncthreads();
            if (tid == 0)
                __hip_atomic_store(&tag1[w * 32], t, __ATOMIC_RELAXED, __HIP_MEMORY_SCOPE_AGENT);

            // ---------- stage2: owner WG (bq==0) handles batch b = kg ----------
            if (bq == 0) {
                const int b = kg;
                if (tid < 64) {
                    int v;
                    do {
                        __builtin_amdgcn_s_sleep(1);
                        v = __hip_atomic_load(&tag1[(tid * 4 + (b >> 4)) * 32],
                                              __ATOMIC_RELAXED, __HIP_MEMORY_SCOPE_AGENT);
                    } while (v < t);
                }
                __syncthreads();
                if (tid < 704) {
                    int cc = tid >> 6, kgi = tid & 63;
                    float s = __hip_atomic_load(&pbuf[(long)(b * 11 + cc) * 64 + kgi],
                                                __ATOMIC_RELAXED, __HIP_MEMORY_SCOPE_AGENT);
                    #pragma unroll
                    for (int off = 32; off; off >>= 1) s += __shfl_down(s, off);
                    if (kgi == 0) slog[cc] = s + p.b2[cc];
                }
                __syncthreads();
                if (tid == 0) {
                    float best = -3.4e38f; int am = 0;
                    #pragma unroll
                    for (int cc = 0; cc < 11; ++cc) {
                        float v = slog[cc];
                        p.out[(long)b * (Tn * 11) + (long)(t - 1) * 11 + cc] = v;
                        if (v > best) { best = v; am = cc; }
                    }
                    __hip_atomic_store(&ptag[b * 32], (t << 4) | am,
                                       __ATOMIC_RELAXED, __HIP_MEMORY_SCOPE_AGENT);
                }
            }
        }
        if (t == Tn) break;

        // ---------- gates0: 32 rows (8 k x 4 gates) x 16 batches, K=768 ----------
        {
            Seg sg[2];
            sg[0] = { p.mainf + (long)t * 256, (long)Tn * 256, 0, 256, Wcomb, 256, 0, 0 };
            sg[1] = { h0T + prv * 32768, 0, 1, 512, p.Whh0, 512, 0, 1 };
            mm_run<32, 4>(sg, kg * 8, 512, bq, tid, actA, actB, wA, wB, redw, redf);
            if (tid < 16) {
                if (t >= 1) {
                    int v;
                    do {
                        __builtin_amdgcn_s_sleep(1);
                        v = __hip_atomic_load(&ptag[(bq * 16 + tid) * 32],
                                              __ATOMIC_RELAXED, __HIP_MEMORY_SCOPE_AGENT);
                    } while ((v >> 4) < t);
                    prevlS[tid] = v & 15;
                } else prevlS[tid] = 0;
            }
            __syncthreads();
            if (tid < 512) {
                int rr = tid >> 4, bb = tid & 15;
                int jrow = (rr >> 3) * 512 + kg * 8 + (rr & 7);
                redf[rr * 17 + bb] += bc0v[jrow] + embg[prevlS[bb] * 2048 + jrow];
            }
            __syncthreads();
            if (tid < 128) {
                int jj = tid >> 4, bb = tid & 15;
                int k = kg * 8 + jj, b = bq * 16 + bb;
                float g0 = redf[jj * 17 + bb];
                float g1 = redf[(8 + jj) * 17 + bb];
                float g2 = redf[(16 + jj) * 17 + bb];
                float g3 = redf[(24 + jj) * 17 + bb];
                float ci = c0T[k * 64 + b];
                float cn = sigm(g1) * ci + sigm(g0) * tanhf(g2);
                c0T[k * 64 + b] = cn;                 // WG-private across steps
                coh_store(&h0T[cur * 32768 + k * 64 + b], sigm(g3) * tanhf(cn));
            }
        }
        gsync(done, arr, w, ++gen);

        // ---------- gates1: K=1024 ----------
        {
            Seg sg[2];
            sg[0] = { h0T + cur * 32768, 0, 1, 512, p.Wih1, 512, 0, 1 };
            sg[1] = { h1T + prv * 32768, 0, 1, 512, p.Whh1, 512, 0, 1 };
            mm_run<32, 4>(sg, kg * 8, 512, bq, tid, actA, actB, wA, wB, redw, redf);
            if (tid < 512) {
                int rr = tid >> 4, bb = tid & 15;
                int jrow = (rr >> 3) * 512 + kg * 8 + (rr & 7);
                redf[rr * 17 + bb] += p.bih1[jrow] + p.bhh1[jrow];
            }
            __syncthreads();
            if (tid < 128) {
                int jj = tid >> 4, bb = tid & 15;
                int k = kg * 8 + jj, b = bq * 16 + bb;
                float g0 = redf[jj * 17 + bb];
                float g1 = redf[(8 + jj) * 17 + bb];
                float g2 = redf[(16 + jj) * 17 + bb];
                float g3 = redf[(24 + jj) * 17 + bb];
                float ci = c1T[k * 64 + b];
                float cn = sigm(g1) * ci + sigm(g0) * tanhf(g2);
                c1T[k * 64 + b] = cn;
                coh_store(&h1T[cur * 32768 + k * 64 + b], sigm(g3) * tanhf(cn));
            }
        }
        gsync(done, arr, w, ++gen);
    }
}

// ---------------- launch ----------------
extern "C" void kernel_launch(void* const* d_in, const int* in_sizes, int n_in,
                              void* d_out, int out_size, void* d_ws, size_t ws_size,
                              hipStream_t stream) {
    const float* mainf = (const float*)d_in[0];
    const float* phys  = (const float*)d_in[1];
    // d_in[2] = mask (unused)
    const float* Wp   = (const float*)d_in[3];
    const float* bp   = (const float*)d_in[4];
    const float* emb  = (const float*)d_in[5];
    const float* Wih0 = (const float*)d_in[6];
    const float* Whh0 = (const float*)d_in[7];
    const float* bih0 = (const float*)d_in[8];
    const float* bhh0 = (const float*)d_in[9];
    const float* Wih1 = (const float*)d_in[10];
    const float* Whh1 = (const float*)d_in[11];
    const float* bih1 = (const float*)d_in[12];
    const float* bhh1 = (const float*)d_in[13];
    const float* W1   = (const float*)d_in[14];
    const float* b1   = (const float*)d_in[15];
    const float* W2   = (const float*)d_in[16];
    const float* b2   = (const float*)d_in[17];
    float* out = (float*)d_out;
    float* ws  = (float*)d_ws;

    (void)hipMemsetAsync(out + OUT_LOGITS_WORDS, 0, (size_t)OUT_TAIL_WORDS * 4, stream);

    k_wcomb<<<2048, 256, 0, stream>>>(Wih0, Wp, bp, bih0, bhh0, ws);
    k_embg<<<88, 256, 0, stream>>>(emb, Wih0, ws);
    k_zero<<<(ZERO_WORDS + 255) / 256, 256, 0, stream>>>(ws);

    MP p{ mainf, phys, Whh0, Wih1, Whh1, bih1, bhh1, W1, b1, W2, b2, ws, out };
    k_main<<<NWG, NTH, 0, stream>>>(p);
}

// Round 11
// 20900.470 us; speedup vs baseline: 1.0636x; 1.0636x over previous
//
#include <hip/hip_runtime.h>

// ---------------- problem constants ----------------
#define Tn   512
#define NWG  256
#define NTH  1024

// ---------------- ws layout (float words) ----------------
#define OFF_WCOMB 0                      // [2048][256]
#define OFF_BC0   524288                 // [2048]
#define OFF_EMBG  526336                 // [11][2048]
#define OFF_H0T   548864                 // [2][512*64] k-major (zero region start)
#define OFF_H1T   (OFF_H0T + 65536)      // [2][512*64]
#define OFF_C0T   (OFF_H1T + 65536)      // [512*64]
#define OFF_C1T   (OFF_C0T + 32768)
#define OFF_BAR   (OFF_C1T + 32768)      // done flag (32 words)
#define OFF_ARR   (OFF_BAR + 32)         // 256 arrival slots * 32
#define OFF_TAG1  (OFF_ARR + 8192)       // 256 head tags * 32 (logical id)
#define OFF_PTAG  (OFF_TAG1 + 8192)      // 64 prev tags * 32
#define ZERO_END  (OFF_PTAG + 2048)
#define ZERO_WORDS (ZERO_END - OFF_H0T)
#define OFF_PBUF  ZERO_END               // [704][64] floats used (region larger)
#define WS_WORDS  (OFF_PBUF + 704 * 256)

// out layout: logits [64][512][11] = 360448, zeros 360448, attn 32768
#define OUT_LOGITS_WORDS 360448
#define OUT_TAIL_WORDS   393216

// ---------------- setup kernels ----------------
__global__ void k_wcomb(const float* __restrict__ Wih0, const float* __restrict__ Wp,
                        const float* __restrict__ bp, const float* __restrict__ bih0,
                        const float* __restrict__ bhh0, float* __restrict__ ws) {
    int j = blockIdx.x;            // 0..2047
    int k = threadIdx.x;           // 0..255
    const float* row = Wih0 + (long)j * 1024;
    float acc = 0.f;
    for (int h = 0; h < 512; ++h) acc = fmaf(row[h], Wp[h * 256 + k], acc);
    ws[OFF_WCOMB + j * 256 + k] = acc;
    __shared__ float s[256];
    s[k] = row[k] * bp[k] + row[256 + k] * bp[256 + k];
    __syncthreads();
    for (int st = 128; st > 0; st >>= 1) { if (k < st) s[k] += s[k + st]; __syncthreads(); }
    if (k == 0) ws[OFF_BC0 + j] = bih0[j] + bhh0[j] + s[0];
}

__global__ void k_embg(const float* __restrict__ emb, const float* __restrict__ Wih0,
                       float* __restrict__ ws) {
    int cls = blockIdx.x >> 3;
    int j = ((blockIdx.x & 7) << 8) + threadIdx.x;
    const float* er = emb + cls * 512;
    const float* wr = Wih0 + (long)j * 1024 + 512;
    float acc = 0.f;
    for (int h = 0; h < 512; ++h) acc = fmaf(er[h], wr[h], acc);
    ws[OFF_EMBG + cls * 2048 + j] = acc;
}

// zero state + tags/barrier (MUST run every launch: graph replays reuse ws)
__global__ void k_zero(float* __restrict__ ws) {
    long i = (long)blockIdx.x * blockDim.x + threadIdx.x;
    if (i < ZERO_WORDS) ws[OFF_H0T + i] = 0.f;
}

// ---------------- main persistent kernel ----------------
struct MP {
    const float *mainf, *phys, *Whh0, *Wih1, *Whh1, *bih1, *bhh1, *W1, *b1, *W2, *b2;
    float* ws;
    float* out;
};

struct Seg {
    const float* act;   // base (batch offset applied inside)
    long rs;            // row stride for b-major
    int kmaj;           // 1: act[k*64+b]  0: act[b*rs+k]
    int klen;
    const float* wgt;   // weight base, row-major
    int wld;
    int wcol0;
    int coh;            // 1: coherent sc0/sc1 staging (cross-XCD data)
};

__device__ __forceinline__ float sigm(float x) { return 1.f / (1.f + expf(-x)); }

__device__ __forceinline__ void coh_issue16(const float* p, float4& v) {
    asm volatile("global_load_dwordx4 %0, %1, off sc0 sc1" : "=&v"(v) : "v"(p));
}
__device__ __forceinline__ void vm_wait0() {
    asm volatile("s_waitcnt vmcnt(0)" ::: "memory");
}
__device__ __forceinline__ void coh_store(float* p, float v) {
    __hip_atomic_store(p, v, __ATOMIC_RELAXED, __HIP_MEMORY_SCOPE_AGENT);
}

// CHUNK = 128 k-rows per staged tile.
__device__ __forceinline__ void resolve(int ch, int nch0, const Seg* sg, int& s, int& k0, int& kc) {
    if (ch < nch0) { s = 0; k0 = ch << 7; }
    else           { s = 1; k0 = (ch - nch0) << 7; }
    kc = sg[s].klen - k0; if (kc > 128) kc = 128;
}

// rows rg*NRH+jr, batch-float4 b4 (batches 4b4..4b4+3 of the WG's 16), k-slice q.
template <int NRH>
__device__ __forceinline__ void comp_tile(const float (*at)[20], const float (*wv)[132],
                                          int rg, int q, int b4, float* acc) {
    float4 a0 = *(const float4*)&at[4 * q + 0][b4 << 2];
    float4 a1 = *(const float4*)&at[4 * q + 1][b4 << 2];
    float4 a2 = *(const float4*)&at[4 * q + 2][b4 << 2];
    float4 a3 = *(const float4*)&at[4 * q + 3][b4 << 2];
    #pragma unroll
    for (int jr = 0; jr < NRH; ++jr) {
        float4 w4 = *(const float4*)&wv[rg * NRH + jr][q << 2];
        acc[jr * 4 + 0] = fmaf(w4.x, a0.x, acc[jr * 4 + 0]);
        acc[jr * 4 + 0] = fmaf(w4.y, a1.x, acc[jr * 4 + 0]);
        acc[jr * 4 + 0] = fmaf(w4.z, a2.x, acc[jr * 4 + 0]);
        acc[jr * 4 + 0] = fmaf(w4.w, a3.x, acc[jr * 4 + 0]);
        acc[jr * 4 + 1] = fmaf(w4.x, a0.y, acc[jr * 4 + 1]);
        acc[jr * 4 + 1] = fmaf(w4.y, a1.y, acc[jr * 4 + 1]);
        acc[jr * 4 + 1] = fmaf(w4.z, a2.y, acc[jr * 4 + 1]);
        acc[jr * 4 + 1] = fmaf(w4.w, a3.y, acc[jr * 4 + 1]);
        acc[jr * 4 + 2] = fmaf(w4.x, a0.z, acc[jr * 4 + 2]);
        acc[jr * 4 + 2] = fmaf(w4.y, a1.z, acc[jr * 4 + 2]);
        acc[jr * 4 + 2] = fmaf(w4.z, a2.z, acc[jr * 4 + 2]);
        acc[jr * 4 + 2] = fmaf(w4.w, a3.z, acc[jr * 4 + 2]);
        acc[jr * 4 + 3] = fmaf(w4.x, a0.w, acc[jr * 4 + 3]);
        acc[jr * 4 + 3] = fmaf(w4.y, a1.w, acc[jr * 4 + 3]);
        acc[jr * 4 + 3] = fmaf(w4.z, a2.w, acc[jr * 4 + 3]);
        acc[jr * 4 + 3] = fmaf(w4.w, a3.w, acc[jr * 4 + 3]);
    }
}

// Computes, for this WG's 16 batches (bq*16..+15) and NR rows
// j(r) = (r>>3)*jstride + j0 + (r&7), the dots over both segments.
// Results land in redf[r*17 + bb] (r<NR, bb<16). Hazard skeleton = r8/r9-proven.
template <int NR, int NRH>
__device__ void mm_run(const Seg* sg, int j0, int jstride, int bq, int tid,
                       float (*actA)[20], float (*actB)[20],
                       float (*wA)[132], float (*wB)[132],
                       float* redw, float* redf) {
    constexpr int NA = NRH * 4;
    const int b4 = tid & 3;
    const int q  = (tid >> 2) & 31;
    const int rg = tid >> 7;
    const int nch0 = (sg[0].klen + 127) >> 7;
    const int nch  = nch0 + ((sg[1].klen + 127) >> 7);
    const int nq0  = (nch + 1) >> 1;
    float acc[NA];
    #pragma unroll
    for (int i = 0; i < NA; ++i) acc[i] = 0.f;

    for (int it = 0; it < nq0; ++it) {
        const int chA = it, chB = nq0 + it;
        const bool hasB = chB < nch;
        int sA, kA, kcA; resolve(chA, nch0, sg, sA, kA, kcA);
        int sB = 0, kB = 0, kcB = 0;
        if (hasB) resolve(chB, nch0, sg, sB, kB, kcB);
        const Seg gA = sg[sA];
        const Seg gB = sg[sB];

        // ---- act staging: threads 0..511 stage buffer A, 512..1023 buffer B ----
        const int abuf = tid >> 9;           // wave-uniform
        const int st   = tid & 511;
        const Seg* gS  = abuf ? &gB : &gA;
        const int  kS  = abuf ? kB : kA;
        const int  kcS = abuf ? kcB : kcA;
        const bool bufOK = abuf ? hasB : true;
        float4 av;
        bool fAct = false;
        if (bufOK) {
            if (gS->kmaj) {
                int kk = st >> 2, b4f = st & 3;
                if (kk < kcS) {
                    const float* pp = gS->act + ((long)(kS + kk) << 6) + (bq << 4) + (b4f << 2);
                    fAct = true;
                    if (gS->coh) coh_issue16(pp, av); else av = *(const float4*)pp;
                }
            } else {
                int k4 = st >> 4, bb = st & 15;
                if ((k4 << 2) < kcS) {
                    const float* pp = gS->act + (long)(bq * 16 + bb) * gS->rs + kS + (k4 << 2);
                    fAct = true;
                    if (gS->coh) coh_issue16(pp, av); else av = *(const float4*)pp;
                }
            }
        }
        // ---- weight staging: all threads, float4; rw = tid>>5 row, kq = tid&31 ----
        float4 wva, wvb;
        bool fWA = false, fWB = false;
        const int rw = tid >> 5, kq = tid & 31;
        if (rw < NR) {
            int j = (rw >> 3) * jstride + j0 + (rw & 7);
            if ((kq << 2) < kcA) {
                wva = *(const float4*)(gA.wgt + (long)j * gA.wld + gA.wcol0 + kA + (kq << 2));
                fWA = true;
            }
            if (hasB && (kq << 2) < kcB) {
                wvb = *(const float4*)(gB.wgt + (long)j * gB.wld + gB.wcol0 + kB + (kq << 2));
                fWB = true;
            }
        }
        vm_wait0();
        // ---- LDS writes ----
        if (fAct) {
            float (*dst)[20] = abuf ? actB : actA;
            if (gS->kmaj) {
                int kk = st >> 2, b4f = st & 3;
                *(float4*)&dst[kk][b4f << 2] = av;
            } else {
                int k4 = st >> 4, bb = st & 15;
                dst[(k4 << 2) + 0][bb] = av.x; dst[(k4 << 2) + 1][bb] = av.y;
                dst[(k4 << 2) + 2][bb] = av.z; dst[(k4 << 2) + 3][bb] = av.w;
            }
        }
        if (fWA) *(float4*)&wA[rw][kq << 2] = wva;
        if (fWB) *(float4*)&wB[rw][kq << 2] = wvb;
        __syncthreads();
        // ---- compute ----
        if (4 * q < kcA) comp_tile<NRH>(actA, wA, rg, q, b4, acc);
        if (hasB && 4 * q < kcB) comp_tile<NRH>(actB, wB, rg, q, b4, acc);
        __syncthreads();
    }
    // ---- reduce 32 q-slices: 16 in-wave (lane bits 2..5), 2 across wave-pairs ----
    #pragma unroll
    for (int i = 0; i < NA; ++i) {
        acc[i] += __shfl_xor(acc[i], 4);
        acc[i] += __shfl_xor(acc[i], 8);
        acc[i] += __shfl_xor(acc[i], 16);
        acc[i] += __shfl_xor(acc[i], 32);
    }
    const int wv5 = tid >> 6, lane = tid & 63;
    const int q4 = wv5 & 1, rgw = wv5 >> 1;
    if (q4 == 1 && lane < 4) {
        const int base = (rgw * 4 + lane) * 17;
        #pragma unroll
        for (int i = 0; i < NA; ++i) redw[base + i] = acc[i];
    }
    __syncthreads();
    if (q4 == 0 && lane < 4) {
        const int base = (rgw * 4 + lane) * 17;
        #pragma unroll
        for (int i = 0; i < NA; ++i) acc[i] += redw[base + i];
        #pragma unroll
        for (int jr = 0; jr < NRH; ++jr)
            #pragma unroll
            for (int jb = 0; jb < 4; ++jb)
                redf[(rgw * NRH + jr) * 17 + lane * 4 + jb] = acc[jr * 4 + jb];
    }
    __syncthreads();
}

// Hierarchical barrier (r6-proven, stable).
__device__ __forceinline__ void gsync(int* done, int* arr, int w, int gen) {
    vm_wait0();
    __syncthreads();
    const int tid = threadIdx.x;
    if (tid == 0)
        __hip_atomic_store(&arr[w * 32], gen, __ATOMIC_RELAXED, __HIP_MEMORY_SCOPE_AGENT);
    if (w == 0) {
        if (tid < NWG) {
            int v;
            do {
                __builtin_amdgcn_s_sleep(1);
                v = __hip_atomic_load(&arr[tid * 32], __ATOMIC_RELAXED, __HIP_MEMORY_SCOPE_AGENT);
            } while (v < gen);
        }
        __syncthreads();
        if (tid == 0)
            __hip_atomic_store(done, gen, __ATOMIC_RELAXED, __HIP_MEMORY_SCOPE_AGENT);
    } else {
        if (tid == 0) {
            int v;
            do {
                __builtin_amdgcn_s_sleep(2);
                v = __hip_atomic_load(done, __ATOMIC_RELAXED, __HIP_MEMORY_SCOPE_AGENT);
            } while (v < gen);
        }
    }
    __syncthreads();
}

__global__ void __launch_bounds__(NTH, 4) k_main(MP p) {
    float* ws = p.ws;
    const float* Wcomb = ws + OFF_WCOMB;
    const float* bc0v  = ws + OFF_BC0;
    const float* embg  = ws + OFF_EMBG;
    float* h0T = ws + OFF_H0T;
    float* h1T = ws + OFF_H1T;
    float* c0T = ws + OFF_C0T;
    float* c1T = ws + OFF_C1T;
    float* pbuf = ws + OFF_PBUF;            // [704][64] used
    int* done = (int*)(ws + OFF_BAR);
    int* arr  = (int*)(ws + OFF_ARR);
    int* tag1 = (int*)(ws + OFF_TAG1);      // indexed by LOGICAL id kg*4+bq
    int* ptag = (int*)(ws + OFF_PTAG);

    __shared__ float actA[128][20], actB[128][20];   // 20.5 KB
    __shared__ float wA[32][132], wB[32][132];       // 33.8 KB
    __shared__ float redw[8 * 4 * 17];               //  2.2 KB
    __shared__ float redf[32 * 17];                  //  2.2 KB
    __shared__ float rrowS[8][17];
    __shared__ float slog[11];
    __shared__ int prevlS[16];

    const int w = blockIdx.x, tid = threadIdx.x;
    // XCD-aware remap (T1): physical WG w lands on XCD w%8. Make the 4
    // batch-quarter WGs that share k-group kg co-resident on ONE XCD so their
    // (identical) weight rows are fetched once and stay L2-resident:
    //   kg % 8 == w % 8  for all 4 bq's.
    const int xcd = w & 7, rr_w = w >> 3;
    const int bq = rr_w & 3;                 // batch quarter 0..3
    const int kg = xcd + 8 * (rr_w >> 2);    // k-group 0..63
    const int lid = kg * 4 + bq;             // logical id for tags
    int gen = 0;

    for (int t = 0; t <= Tn; ++t) {
        const int cur = t & 1, prv = cur ^ 1;

        // ---------- head for step t-1: 8 W1-rows (kg*8..+7) x 16 batches ----------
        if (t >= 1) {
            Seg sg[2];
            sg[0] = { h1T + prv * 32768, 0, 1, 512, p.W1, 544, 0, 1 };
            sg[1] = { p.phys + (long)(t - 1) * 32, (long)Tn * 32, 0, 32, p.W1, 544, 512, 0 };
            mm_run<8, 1>(sg, kg * 8, 0, bq, tid, actA, actB, wA, wB, redw, redf);
            if (tid < 128) {
                int rr = tid >> 4, bb = tid & 15;
                float hv = redf[rr * 17 + bb] + p.b1[kg * 8 + rr];
                rrowS[rr][bb] = hv > 0.f ? hv : 0.f;
            }
            __syncthreads();
            if (tid < 176) {
                int bb = tid / 11, cc = tid - bb * 11;
                float s = 0.f;
                #pragma unroll
                for (int r = 0; r < 8; ++r)
                    s = fmaf(rrowS[r][bb], p.W2[cc * 512 + kg * 8 + r], s);
                int b = bq * 16 + bb;
                coh_store(&pbuf[(long)(b * 11 + cc) * 64 + kg], s);
            }
            vm_wait0();              // every wave drains its own pbuf stores
            __syncthreads();
            if (tid == 0)
                __hip_atomic_store(&tag1[lid * 32], t, __ATOMIC_RELAXED, __HIP_MEMORY_SCOPE_AGENT);

            // ---------- stage2: owner WG (bq==0) handles batch b = kg ----------
            if (bq == 0) {
                const int b = kg;
                if (tid < 64) {
                    int v;
                    do {
                        __builtin_amdgcn_s_sleep(1);
                        v = __hip_atomic_load(&tag1[(tid * 4 + (b >> 4)) * 32],
                                              __ATOMIC_RELAXED, __HIP_MEMORY_SCOPE_AGENT);
                    } while (v < t);
                }
                __syncthreads();
                if (tid < 704) {
                    int cc = tid >> 6, kgi = tid & 63;
                    float s = __hip_atomic_load(&pbuf[(long)(b * 11 + cc) * 64 + kgi],
                                                __ATOMIC_RELAXED, __HIP_MEMORY_SCOPE_AGENT);
                    #pragma unroll
                    for (int off = 32; off; off >>= 1) s += __shfl_down(s, off);
                    if (kgi == 0) slog[cc] = s + p.b2[cc];
                }
                __syncthreads();
                if (tid == 0) {
                    float best = -3.4e38f; int am = 0;
                    #pragma unroll
                    for (int cc = 0; cc < 11; ++cc) {
                        float v = slog[cc];
                        p.out[(long)b * (Tn * 11) + (long)(t - 1) * 11 + cc] = v;
                        if (v > best) { best = v; am = cc; }
                    }
                    __hip_atomic_store(&ptag[b * 32], (t << 4) | am,
                                       __ATOMIC_RELAXED, __HIP_MEMORY_SCOPE_AGENT);
                }
            }
        }
        if (t == Tn) break;

        // ---------- gates0: 32 rows (8 k x 4 gates) x 16 batches, K=768 ----------
        {
            Seg sg[2];
            sg[0] = { p.mainf + (long)t * 256, (long)Tn * 256, 0, 256, Wcomb, 256, 0, 0 };
            sg[1] = { h0T + prv * 32768, 0, 1, 512, p.Whh0, 512, 0, 1 };
            mm_run<32, 4>(sg, kg * 8, 512, bq, tid, actA, actB, wA, wB, redw, redf);
            if (tid < 16) {
                if (t >= 1) {
                    int v;
                    do {
                        __builtin_amdgcn_s_sleep(1);
                        v = __hip_atomic_load(&ptag[(bq * 16 + tid) * 32],
                                              __ATOMIC_RELAXED, __HIP_MEMORY_SCOPE_AGENT);
                    } while ((v >> 4) < t);
                    prevlS[tid] = v & 15;
                } else prevlS[tid] = 0;
            }
            __syncthreads();
            if (tid < 512) {
                int rr = tid >> 4, bb = tid & 15;
                int jrow = (rr >> 3) * 512 + kg * 8 + (rr & 7);
                redf[rr * 17 + bb] += bc0v[jrow] + embg[prevlS[bb] * 2048 + jrow];
            }
            __syncthreads();
            if (tid < 128) {
                int jj = tid >> 4, bb = tid & 15;
                int k = kg * 8 + jj, b = bq * 16 + bb;
                float g0 = redf[jj * 17 + bb];
                float g1 = redf[(8 + jj) * 17 + bb];
                float g2 = redf[(16 + jj) * 17 + bb];
                float g3 = redf[(24 + jj) * 17 + bb];
                float ci = c0T[k * 64 + b];
                float cn = sigm(g1) * ci + sigm(g0) * tanhf(g2);
                c0T[k * 64 + b] = cn;                 // WG-private across steps
                coh_store(&h0T[cur * 32768 + k * 64 + b], sigm(g3) * tanhf(cn));
            }
        }
        gsync(done, arr, w, ++gen);

        // ---------- gates1: K=1024 ----------
        {
            Seg sg[2];
            sg[0] = { h0T + cur * 32768, 0, 1, 512, p.Wih1, 512, 0, 1 };
            sg[1] = { h1T + prv * 32768, 0, 1, 512, p.Whh1, 512, 0, 1 };
            mm_run<32, 4>(sg, kg * 8, 512, bq, tid, actA, actB, wA, wB, redw, redf);
            if (tid < 512) {
                int rr = tid >> 4, bb = tid & 15;
                int jrow = (rr >> 3) * 512 + kg * 8 + (rr & 7);
                redf[rr * 17 + bb] += p.bih1[jrow] + p.bhh1[jrow];
            }
            __syncthreads();
            if (tid < 128) {
                int jj = tid >> 4, bb = tid & 15;
                int k = kg * 8 + jj, b = bq * 16 + bb;
                float g0 = redf[jj * 17 + bb];
                float g1 = redf[(8 + jj) * 17 + bb];
                float g2 = redf[(16 + jj) * 17 + bb];
                float g3 = redf[(24 + jj) * 17 + bb];
                float ci = c1T[k * 64 + b];
                float cn = sigm(g1) * ci + sigm(g0) * tanhf(g2);
                c1T[k * 64 + b] = cn;
                coh_store(&h1T[cur * 32768 + k * 64 + b], sigm(g3) * tanhf(cn));
            }
        }
        gsync(done, arr, w, ++gen);
    }
}

// ---------------- launch ----------------
extern "C" void kernel_launch(void* const* d_in, const int* in_sizes, int n_in,
                              void* d_out, int out_size, void* d_ws, size_t ws_size,
                              hipStream_t stream) {
    const float* mainf = (const float*)d_in[0];
    const float* phys  = (const float*)d_in[1];
    // d_in[2] = mask (unused)
    const float* Wp   = (const float*)d_in[3];
    const float* bp   = (const float*)d_in[4];
    const float* emb  = (const float*)d_in[5];
    const float* Wih0 = (const float*)d_in[6];
    const float* Whh0 = (const float*)d_in[7];
    const float* bih0 = (const float*)d_in[8];
    const float* bhh0 = (const float*)d_in[9];
    const float* Wih1 = (const float*)d_in[10];
    const float* Whh1 = (const float*)d_in[11];
    const float* bih1 = (const float*)d_in[12];
    const float* bhh1 = (const float*)d_in[13];
    const float* W1   = (const float*)d_in[14];
    const float* b1   = (const float*)d_in[15];
    const float* W2   = (const float*)d_in[16];
    const float* b2   = (const float*)d_in[17];
    float* out = (float*)d_out;
    float* ws  = (float*)d_ws;

    (void)hipMemsetAsync(out + OUT_LOGITS_WORDS, 0, (size_t)OUT_TAIL_WORDS * 4, stream);

    k_wcomb<<<2048, 256, 0, stream>>>(Wih0, Wp, bp, bih0, bhh0, ws);
    k_embg<<<88, 256, 0, stream>>>(emb, Wih0, ws);
    k_zero<<<(ZERO_WORDS + 255) / 256, 256, 0, stream>>>(ws);

    MP p{ mainf, phys, Whh0, Wih1, Whh1, bih1, bhh1, W1, b1, W2, b2, ws, out };
    k_main<<<NWG, NTH, 0, stream>>>(p);
}

// Round 12
// 16911.389 us; speedup vs baseline: 1.3144x; 1.2359x over previous
//
#include <hip/hip_runtime.h>

// ---------------- problem constants ----------------
#define Tn   512
#define NWG  256
#define NTH  1024

// ---------------- ws layout (float words) ----------------
#define OFF_WCOMB 0                      // [2048][256]
#define OFF_BC0   524288                 // [2048]
#define OFF_EMBG  526336                 // [11][2048]
#define OFF_H0T   548864                 // [2][512*64] k-major (zero region start)
#define OFF_H1T   (OFF_H0T + 65536)      // [2][512*64]
#define OFF_C0T   (OFF_H1T + 65536)      // [512*64]
#define OFF_C1T   (OFF_C0T + 32768)
#define OFF_BAR   (OFF_C1T + 32768)      // done flag (32 words)
#define OFF_ARR   (OFF_BAR + 32)         // 256 arrival slots * 32
#define OFF_TAG1  (OFF_ARR + 8192)       // 256 head tags * 32
#define OFF_PTAG  (OFF_TAG1 + 8192)      // 64 prev tags * 32
#define ZERO_END  (OFF_PTAG + 2048)
#define ZERO_WORDS (ZERO_END - OFF_H0T)
#define OFF_PBUF  ZERO_END               // [704][128] floats used
#define WS_WORDS  (OFF_PBUF + 704 * 256)

// out layout: logits [64][512][11] = 360448, zeros 360448, attn 32768
#define OUT_LOGITS_WORDS 360448
#define OUT_TAIL_WORDS   393216

// ---------------- setup kernels ----------------
__global__ void k_wcomb(const float* __restrict__ Wih0, const float* __restrict__ Wp,
                        const float* __restrict__ bp, const float* __restrict__ bih0,
                        const float* __restrict__ bhh0, float* __restrict__ ws) {
    int j = blockIdx.x;            // 0..2047
    int k = threadIdx.x;           // 0..255
    const float* row = Wih0 + (long)j * 1024;
    float acc = 0.f;
    for (int h = 0; h < 512; ++h) acc = fmaf(row[h], Wp[h * 256 + k], acc);
    ws[OFF_WCOMB + j * 256 + k] = acc;
    __shared__ float s[256];
    s[k] = row[k] * bp[k] + row[256 + k] * bp[256 + k];
    __syncthreads();
    for (int st = 128; st > 0; st >>= 1) { if (k < st) s[k] += s[k + st]; __syncthreads(); }
    if (k == 0) ws[OFF_BC0 + j] = bih0[j] + bhh0[j] + s[0];
}

__global__ void k_embg(const float* __restrict__ emb, const float* __restrict__ Wih0,
                       float* __restrict__ ws) {
    int cls = blockIdx.x >> 3;
    int j = ((blockIdx.x & 7) << 8) + threadIdx.x;
    const float* er = emb + cls * 512;
    const float* wr = Wih0 + (long)j * 1024 + 512;
    float acc = 0.f;
    for (int h = 0; h < 512; ++h) acc = fmaf(er[h], wr[h], acc);
    ws[OFF_EMBG + cls * 2048 + j] = acc;
}

// zero state + tags/barrier (MUST run every launch: graph replays reuse ws)
__global__ void k_zero(float* __restrict__ ws) {
    long i = (long)blockIdx.x * blockDim.x + threadIdx.x;
    if (i < ZERO_WORDS) ws[OFF_H0T + i] = 0.f;
}

// ---------------- main persistent kernel ----------------
struct MP {
    const float *mainf, *phys, *Whh0, *Wih1, *Whh1, *bih1, *bhh1, *W1, *b1, *W2, *b2;
    float* ws;
    float* out;
};

__device__ __forceinline__ float sigm(float x) { return 1.f / (1.f + expf(-x)); }

__device__ __forceinline__ void coh_issue16(const float* p, float4& v) {
    asm volatile("global_load_dwordx4 %0, %1, off sc0 sc1" : "=&v"(v) : "v"(p));
}
__device__ __forceinline__ void vm_wait0() {
    asm volatile("s_waitcnt vmcnt(0)" ::: "memory");
}
__device__ __forceinline__ void coh_store(float* p, float v) {
    __hip_atomic_store(p, v, __ATOMIC_RELAXED, __HIP_MEMORY_SCOPE_AGENT);
}

// 16 FMAs: row-quad (rg*4+jr), 4 batches (4*b4..+3), k-slice q within chunk.
__device__ __forceinline__ void comp_g(const float (*at)[36], const float* wp, int wld, int kA,
                                       int rg, int q, int b4, float* acc) {
    float4 a0 = *(const float4*)&at[(q << 2) + 0][b4 << 2];
    float4 a1 = *(const float4*)&at[(q << 2) + 1][b4 << 2];
    float4 a2 = *(const float4*)&at[(q << 2) + 2][b4 << 2];
    float4 a3 = *(const float4*)&at[(q << 2) + 3][b4 << 2];
#pragma unroll
    for (int jr = 0; jr < 4; ++jr) {
        float4 w4 = *(const float4*)(wp + (long)((rg << 2) + jr) * wld + kA + (q << 2));
        acc[jr * 4 + 0] = fmaf(w4.x, a0.x, acc[jr * 4 + 0]);
        acc[jr * 4 + 0] = fmaf(w4.y, a1.x, acc[jr * 4 + 0]);
        acc[jr * 4 + 0] = fmaf(w4.z, a2.x, acc[jr * 4 + 0]);
        acc[jr * 4 + 0] = fmaf(w4.w, a3.x, acc[jr * 4 + 0]);
        acc[jr * 4 + 1] = fmaf(w4.x, a0.y, acc[jr * 4 + 1]);
        acc[jr * 4 + 1] = fmaf(w4.y, a1.y, acc[jr * 4 + 1]);
        acc[jr * 4 + 1] = fmaf(w4.z, a2.y, acc[jr * 4 + 1]);
        acc[jr * 4 + 1] = fmaf(w4.w, a3.y, acc[jr * 4 + 1]);
        acc[jr * 4 + 2] = fmaf(w4.x, a0.z, acc[jr * 4 + 2]);
        acc[jr * 4 + 2] = fmaf(w4.y, a1.z, acc[jr * 4 + 2]);
        acc[jr * 4 + 2] = fmaf(w4.z, a2.z, acc[jr * 4 + 2]);
        acc[jr * 4 + 2] = fmaf(w4.w, a3.z, acc[jr * 4 + 2]);
        acc[jr * 4 + 3] = fmaf(w4.x, a0.w, acc[jr * 4 + 3]);
        acc[jr * 4 + 3] = fmaf(w4.y, a1.w, acc[jr * 4 + 3]);
        acc[jr * 4 + 3] = fmaf(w4.z, a2.w, acc[jr * 4 + 3]);
        acc[jr * 4 + 3] = fmaf(w4.w, a3.w, acc[jr * 4 + 3]);
    }
}

// Gates GEMM: seg0 (klen NCH0*64, km0/coh0, weights w0 resident, wld0) +
// seg1 (h-state, kmaj coh, K=512, weights w1 resident, wld 512).
// 32 batches (bq), 16 rows. Results -> redf[r*33 + bb]. r8-proven hazard order.
template <int NCH0>
__device__ void mm_g(const float* a0, long rs0, int km0, int coh0,
                     const float* a1,
                     const float* w0, int wld0, const float* w1,
                     int bq, int tid,
                     float (*aA)[36], float (*aB)[36],
                     float* redw, float* redf) {
    constexpr int NQ0 = (NCH0 + 8) / 2;
    const int b4 = tid & 7, q = (tid >> 3) & 15, rg = (tid >> 7) & 3;
    const int st = tid & 511, sb = tid >> 9;
    float acc[16];
#pragma unroll
    for (int i = 0; i < 16; ++i) acc[i] = 0.f;

    for (int it = 0; it < NQ0; ++it) {
        const int ch = sb ? (NQ0 + it) : it;
        float4 av;
        int km;
        {
            const float* base; int k0, coh;
            if (ch < NCH0) { base = a0; k0 = ch << 6; km = km0; coh = coh0; }
            else           { base = a1; k0 = (ch - NCH0) << 6; km = 1; coh = 1; }
            if (km) {
                const int kk = st >> 3, b4f = st & 7;
                const float* pp = base + ((long)(k0 + kk) << 6) + (bq << 5) + (b4f << 2);
                if (coh) coh_issue16(pp, av); else av = *(const float4*)pp;
            } else {
                const int k4 = st >> 5, bb = st & 31;
                av = *(const float4*)(base + (long)((bq << 5) + bb) * rs0 + k0 + (k4 << 2));
            }
        }
        vm_wait0();
        {
            float (*dst)[36] = sb ? aB : aA;
            if (km) {
                const int kk = st >> 3, b4f = st & 7;
                *(float4*)&dst[kk][b4f << 2] = av;
            } else {
                const int k4 = st >> 5, bb = st & 31;
                dst[(k4 << 2) + 0][bb] = av.x; dst[(k4 << 2) + 1][bb] = av.y;
                dst[(k4 << 2) + 2][bb] = av.z; dst[(k4 << 2) + 3][bb] = av.w;
            }
        }
        __syncthreads();
        if (tid < 512) {
            {
                const int cA = it; const float* wp; int wld, kA;
                if (cA < NCH0) { wp = w0; wld = wld0; kA = cA << 6; }
                else           { wp = w1; wld = 512;  kA = (cA - NCH0) << 6; }
                comp_g(aA, wp, wld, kA, rg, q, b4, acc);
            }
            {
                const int cB = NQ0 + it; const float* wp; int wld, kB;
                if (cB < NCH0) { wp = w0; wld = wld0; kB = cB << 6; }
                else           { wp = w1; wld = 512;  kB = (cB - NCH0) << 6; }
                comp_g(aB, wp, wld, kB, rg, q, b4, acc);
            }
        }
        __syncthreads();
    }
    // q-reduce: 8 in-wave slices (lane bits 3..5), then one 2-wave hop (qh bit).
#pragma unroll
    for (int i = 0; i < 16; ++i) {
        acc[i] += __shfl_xor(acc[i], 8);
        acc[i] += __shfl_xor(acc[i], 16);
        acc[i] += __shfl_xor(acc[i], 32);
    }
    const int lane = tid & 63;
    if (tid < 512 && ((tid >> 6) & 1) && lane < 8) {
        float* d = redw + (((rg << 3) + lane) << 4);
#pragma unroll
        for (int i = 0; i < 16; ++i) d[i] = acc[i];
    }
    __syncthreads();
    if (tid < 512 && !((tid >> 6) & 1) && lane < 8) {
        const float* s = redw + (((rg << 3) + lane) << 4);
#pragma unroll
        for (int jr = 0; jr < 4; ++jr)
#pragma unroll
            for (int jb = 0; jb < 4; ++jb)
                redf[((rg << 2) + jr) * 33 + (lane << 2) + jb] = acc[jr * 4 + jb] + s[jr * 4 + jb];
    }
    __syncthreads();
}

// Head: 4 W1 rows (kg*4..+3) x 32 batches; K = 512 (h1, coh) + 32 (phys).
// W1 streamed per chunk into hwA/hwB. Results -> redf[r*33 + bb], r<4.
__device__ void mm_h(const float* h1, const float* physb, long rsp,
                     const float* W1, int kg, int bq, int tid,
                     float (*aA)[36], float (*aB)[36],
                     float (*hwA)[68], float (*hwB)[68],
                     float* redw, float* redf) {
    const int b4 = tid & 7, q = (tid >> 3) & 15, rg = (tid >> 7) & 3;
    const int st = tid & 511, sb = tid >> 9;
    float acc[4] = {0.f, 0.f, 0.f, 0.f};
    for (int it = 0; it < 5; ++it) {
        const int ch = sb ? (5 + it) : it;
        const bool valid = ch < 9;
        float4 av, wv;
        bool fa = false, fw = false;
        if (valid) {
            if (ch < 8) {
                const int kk = st >> 3, b4f = st & 7;
                coh_issue16(h1 + ((long)((ch << 6) + kk) << 6) + (bq << 5) + (b4f << 2), av);
                fa = true;
            } else {
                const int k4 = st >> 5, bb = st & 31;
                if (k4 < 8) {
                    av = *(const float4*)(physb + (long)((bq << 5) + bb) * rsp + (k4 << 2));
                    fa = true;
                }
            }
            if (st < 64) {
                const int rw = st >> 4, kq = st & 15;
                if (ch < 8 || kq < 8) {
                    const int gcol = (ch < 8) ? ((ch << 6) + (kq << 2)) : (512 + (kq << 2));
                    wv = *(const float4*)(W1 + (long)(kg * 4 + rw) * 544 + gcol);
                    fw = true;
                }
            }
        }
        vm_wait0();
        if (fa) {
            float (*dst)[36] = sb ? aB : aA;
            if (ch < 8) { const int kk = st >> 3, b4f = st & 7; *(float4*)&dst[kk][b4f << 2] = av; }
            else { const int k4 = st >> 5, bb = st & 31;
                   dst[(k4 << 2) + 0][bb] = av.x; dst[(k4 << 2) + 1][bb] = av.y;
                   dst[(k4 << 2) + 2][bb] = av.z; dst[(k4 << 2) + 3][bb] = av.w; }
        }
        if (fw) {
            float (*dw)[68] = sb ? hwB : hwA;
            *(float4*)&dw[st >> 4][(st & 15) << 2] = wv;
        }
        __syncthreads();
        if (tid < 512) {
            {   // chunk A = it (kc=64 always)
                float4 a0 = *(const float4*)&aA[(q << 2) + 0][b4 << 2];
                float4 a1v = *(const float4*)&aA[(q << 2) + 1][b4 << 2];
                float4 a2 = *(const float4*)&aA[(q << 2) + 2][b4 << 2];
                float4 a3 = *(const float4*)&aA[(q << 2) + 3][b4 << 2];
                float4 w4 = *(const float4*)&hwA[rg][q << 2];
                acc[0] = fmaf(w4.x, a0.x, acc[0]); acc[0] = fmaf(w4.y, a1v.x, acc[0]);
                acc[0] = fmaf(w4.z, a2.x, acc[0]); acc[0] = fmaf(w4.w, a3.x, acc[0]);
                acc[1] = fmaf(w4.x, a0.y, acc[1]); acc[1] = fmaf(w4.y, a1v.y, acc[1]);
                acc[1] = fmaf(w4.z, a2.y, acc[1]); acc[1] = fmaf(w4.w, a3.y, acc[1]);
                acc[2] = fmaf(w4.x, a0.z, acc[2]); acc[2] = fmaf(w4.y, a1v.z, acc[2]);
                acc[2] = fmaf(w4.z, a2.z, acc[2]); acc[2] = fmaf(w4.w, a3.z, acc[2]);
                acc[3] = fmaf(w4.x, a0.w, acc[3]); acc[3] = fmaf(w4.y, a1v.w, acc[3]);
                acc[3] = fmaf(w4.z, a2.w, acc[3]); acc[3] = fmaf(w4.w, a3.w, acc[3]);
            }
            const int cB = 5 + it;
            const int kc = (cB == 8) ? 32 : 64;
            if (cB < 9 && (q << 2) < kc) {
                float4 a0 = *(const float4*)&aB[(q << 2) + 0][b4 << 2];
                float4 a1v = *(const float4*)&aB[(q << 2) + 1][b4 << 2];
                float4 a2 = *(const float4*)&aB[(q << 2) + 2][b4 << 2];
                float4 a3 = *(const float4*)&aB[(q << 2) + 3][b4 << 2];
                float4 w4 = *(const float4*)&hwB[rg][q << 2];
                acc[0] = fmaf(w4.x, a0.x, acc[0]); acc[0] = fmaf(w4.y, a1v.x, acc[0]);
                acc[0] = fmaf(w4.z, a2.x, acc[0]); acc[0] = fmaf(w4.w, a3.x, acc[0]);
                acc[1] = fmaf(w4.x, a0.y, acc[1]); acc[1] = fmaf(w4.y, a1v.y, acc[1]);
                acc[1] = fmaf(w4.z, a2.y, acc[1]); acc[1] = fmaf(w4.w, a3.y, acc[1]);
                acc[2] = fmaf(w4.x, a0.z, acc[2]); acc[2] = fmaf(w4.y, a1v.z, acc[2]);
                acc[2] = fmaf(w4.z, a2.z, acc[2]); acc[2] = fmaf(w4.w, a3.z, acc[2]);
                acc[3] = fmaf(w4.x, a0.w, acc[3]); acc[3] = fmaf(w4.y, a1v.w, acc[3]);
                acc[3] = fmaf(w4.z, a2.w, acc[3]); acc[3] = fmaf(w4.w, a3.w, acc[3]);
            }
        }
        __syncthreads();
    }
#pragma unroll
    for (int i = 0; i < 4; ++i) {
        acc[i] += __shfl_xor(acc[i], 8);
        acc[i] += __shfl_xor(acc[i], 16);
        acc[i] += __shfl_xor(acc[i], 32);
    }
    const int lane = tid & 63;
    if (tid < 512 && ((tid >> 6) & 1) && lane < 8) {
        float* d = redw + (((rg << 3) + lane) << 4);
#pragma unroll
        for (int i = 0; i < 4; ++i) d[i] = acc[i];
    }
    __syncthreads();
    if (tid < 512 && !((tid >> 6) & 1) && lane < 8) {
        const float* s = redw + (((rg << 3) + lane) << 4);
#pragma unroll
        for (int jb = 0; jb < 4; ++jb)
            redf[rg * 33 + (lane << 2) + jb] = acc[jb] + s[jb];
    }
    __syncthreads();
}

// Hierarchical barrier (r6-proven, stable).
__device__ __forceinline__ void gsync(int* done, int* arr, int w, int gen) {
    vm_wait0();
    __syncthreads();
    const int tid = threadIdx.x;
    if (tid == 0)
        __hip_atomic_store(&arr[w * 32], gen, __ATOMIC_RELAXED, __HIP_MEMORY_SCOPE_AGENT);
    if (w == 0) {
        if (tid < NWG) {
            int v;
            do {
                __builtin_amdgcn_s_sleep(1);
                v = __hip_atomic_load(&arr[tid * 32], __ATOMIC_RELAXED, __HIP_MEMORY_SCOPE_AGENT);
            } while (v < gen);
        }
        __syncthreads();
        if (tid == 0)
            __hip_atomic_store(done, gen, __ATOMIC_RELAXED, __HIP_MEMORY_SCOPE_AGENT);
    } else {
        if (tid == 0) {
            int v;
            do {
                __builtin_amdgcn_s_sleep(2);
                v = __hip_atomic_load(done, __ATOMIC_RELAXED, __HIP_MEMORY_SCOPE_AGENT);
            } while (v < gen);
        }
    }
    __syncthreads();
}

__global__ void __launch_bounds__(NTH, 4) k_main(MP p) {
    float* ws = p.ws;
    const float* bc0v = ws + OFF_BC0;
    const float* embg = ws + OFF_EMBG;
    float* h0T = ws + OFF_H0T;
    float* h1T = ws + OFF_H1T;
    float* c0T = ws + OFF_C0T;
    float* c1T = ws + OFF_C1T;
    float* pbuf = ws + OFF_PBUF;            // [704][128] used
    int* done = (int*)(ws + OFF_BAR);
    int* arr  = (int*)(ws + OFF_ARR);
    int* tag1 = (int*)(ws + OFF_TAG1);
    int* ptag = (int*)(ws + OFF_PTAG);

    // Resident weights (preloaded once, reused for all 512 steps): 112 KB
    __shared__ float Wc_l[16][256];
    __shared__ float W0_l[16][512];
    __shared__ float Wi1_l[16][512];
    __shared__ float Wh1_l[16][512];
    __shared__ float actA[64][36], actB[64][36];     // 18 KB
    __shared__ float hwA[4][68], hwB[4][68];
    __shared__ float redw[512];
    __shared__ float redf[16 * 33];
    __shared__ float rrowS[4][33];
    __shared__ float slog[11];
    __shared__ int prevlS[32];

    const int w = blockIdx.x, tid = threadIdx.x;
    const int kg = w >> 1, bq = w & 1;      // 128 k-groups x 2 batch-halves
    int gen = 0;

    // ---- one-time weight preload (L2-cached reads, never repeated) ----
    for (int e = tid; e < 4096; e += NTH) {
        int r = e >> 8, c = e & 255;
        int j = (r >> 2) * 512 + kg * 4 + (r & 3);
        Wc_l[r][c] = ws[OFF_WCOMB + (long)j * 256 + c];
    }
    for (int e = tid; e < 8192; e += NTH) {
        int r = e >> 9, c = e & 511;
        int j = (r >> 2) * 512 + kg * 4 + (r & 3);
        W0_l[r][c]  = p.Whh0[(long)j * 512 + c];
        Wi1_l[r][c] = p.Wih1[(long)j * 512 + c];
        Wh1_l[r][c] = p.Whh1[(long)j * 512 + c];
    }
    __syncthreads();

    for (int t = 0; t <= Tn; ++t) {
        const int cur = t & 1, prv = cur ^ 1;

        // ---------- head for step t-1 ----------
        if (t >= 1) {
            mm_h(h1T + prv * 32768, p.phys + (long)(t - 1) * 32, (long)Tn * 32,
                 p.W1, kg, bq, tid, actA, actB, hwA, hwB, redw, redf);
            if (tid < 128) {
                int rr = tid >> 5, bb = tid & 31;
                float hv = redf[rr * 33 + bb] + p.b1[kg * 4 + rr];
                rrowS[rr][bb] = hv > 0.f ? hv : 0.f;
            }
            __syncthreads();
            if (tid < 352) {
                int bb = tid / 11, cc = tid - bb * 11;
                float s = 0.f;
#pragma unroll
                for (int r = 0; r < 4; ++r)
                    s = fmaf(rrowS[r][bb], p.W2[cc * 512 + kg * 4 + r], s);
                int b = bq * 32 + bb;
                coh_store(&pbuf[(long)(b * 11 + cc) * 128 + kg], s);
            }
            vm_wait0();
            __syncthreads();
            if (tid == 0)
                __hip_atomic_store(&tag1[w * 32], t, __ATOMIC_RELAXED, __HIP_MEMORY_SCOPE_AGENT);

            // ---------- stage2: owner (bq==0, kg<64) handles batch b = kg ----------
            if (bq == 0 && kg < 64) {
                const int b = kg;
                if (tid < 128) {
                    int v;
                    do {
                        __builtin_amdgcn_s_sleep(1);
                        v = __hip_atomic_load(&tag1[(tid * 2 + (b >> 5)) * 32],
                                              __ATOMIC_RELAXED, __HIP_MEMORY_SCOPE_AGENT);
                    } while (v < t);
                }
                __syncthreads();
                if (tid < 704) {
                    int cc = tid >> 6, kgi = tid & 63;
                    float s = __hip_atomic_load(&pbuf[(long)(b * 11 + cc) * 128 + kgi],
                                                __ATOMIC_RELAXED, __HIP_MEMORY_SCOPE_AGENT)
                            + __hip_atomic_load(&pbuf[(long)(b * 11 + cc) * 128 + kgi + 64],
                                                __ATOMIC_RELAXED, __HIP_MEMORY_SCOPE_AGENT);
#pragma unroll
                    for (int off = 32; off; off >>= 1) s += __shfl_down(s, off);
                    if (kgi == 0) slog[cc] = s + p.b2[cc];
                }
                __syncthreads();
                if (tid == 0) {
                    float best = -3.4e38f; int am = 0;
#pragma unroll
                    for (int cc = 0; cc < 11; ++cc) {
                        float v = slog[cc];
                        p.out[(long)b * (Tn * 11) + (long)(t - 1) * 11 + cc] = v;
                        if (v > best) { best = v; am = cc; }
                    }
                    __hip_atomic_store(&ptag[b * 32], (t << 4) | am,
                                       __ATOMIC_RELAXED, __HIP_MEMORY_SCOPE_AGENT);
                }
            }
        }
        if (t == Tn) break;

        // ---------- gates0: K = 256 (mainf/Wcomb) + 512 (h0 prv/Whh0) ----------
        mm_g<4>(p.mainf + (long)t * 256, (long)Tn * 256, 0, 0,
                h0T + prv * 32768, &Wc_l[0][0], 256, &W0_l[0][0],
                bq, tid, actA, actB, redw, redf);
        if (tid < 32) {
            if (t >= 1) {
                int v;
                do {
                    __builtin_amdgcn_s_sleep(1);
                    v = __hip_atomic_load(&ptag[(bq * 32 + tid) * 32],
                                          __ATOMIC_RELAXED, __HIP_MEMORY_SCOPE_AGENT);
                } while ((v >> 4) < t);
                prevlS[tid] = v & 15;
            } else prevlS[tid] = 0;
        }
        __syncthreads();
        if (tid < 512) {
            int rr = tid >> 5, bb = tid & 31;
            int jrow = (rr >> 2) * 512 + kg * 4 + (rr & 3);
            redf[rr * 33 + bb] += bc0v[jrow] + embg[prevlS[bb] * 2048 + jrow];
        }
        __syncthreads();
        if (tid < 128) {
            int jj = tid >> 5, bb = tid & 31;
            int k = kg * 4 + jj, b = bq * 32 + bb;
            float g0 = redf[jj * 33 + bb];
            float g1 = redf[(4 + jj) * 33 + bb];
            float g2 = redf[(8 + jj) * 33 + bb];
            float g3 = redf[(12 + jj) * 33 + bb];
            float ci = c0T[k * 64 + b];
            float cn = sigm(g1) * ci + sigm(g0) * tanhf(g2);
            c0T[k * 64 + b] = cn;                 // WG-private across steps
            coh_store(&h0T[cur * 32768 + k * 64 + b], sigm(g3) * tanhf(cn));
        }
        gsync(done, arr, w, ++gen);

        // ---------- gates1: K = 512 (h0 cur/Wih1) + 512 (h1 prv/Whh1) ----------
        mm_g<8>(h0T + cur * 32768, 0, 1, 1,
                h1T + prv * 32768, &Wi1_l[0][0], 512, &Wh1_l[0][0],
                bq, tid, actA, actB, redw, redf);
        if (tid < 512) {
            int rr = tid >> 5, bb = tid & 31;
            int jrow = (rr >> 2) * 512 + kg * 4 + (rr & 3);
            redf[rr * 33 + bb] += p.bih1[jrow] + p.bhh1[jrow];
        }
        __syncthreads();
        if (tid < 128) {
            int jj = tid >> 5, bb = tid & 31;
            int k = kg * 4 + jj, b = bq * 32 + bb;
            float g0 = redf[jj * 33 + bb];
            float g1 = redf[(4 + jj) * 33 + bb];
            float g2 = redf[(8 + jj) * 33 + bb];
            float g3 = redf[(12 + jj) * 33 + bb];
            float ci = c1T[k * 64 + b];
            float cn = sigm(g1) * ci + sigm(g0) * tanhf(g2);
            c1T[k * 64 + b] = cn;
            coh_store(&h1T[cur * 32768 + k * 64 + b], sigm(g3) * tanhf(cn));
        }
        gsync(done, arr, w, ++gen);
    }
}

// ---------------- launch ----------------
extern "C" void kernel_launch(void* const* d_in, const int* in_sizes, int n_in,
                              void* d_out, int out_size, void* d_ws, size_t ws_size,
                              hipStream_t stream) {
    const float* mainf = (const float*)d_in[0];
    const float* phys  = (const float*)d_in[1];
    // d_in[2] = mask (unused)
    const float* Wp   = (const float*)d_in[3];
    const float* bp   = (const float*)d_in[4];
    const float* emb  = (const float*)d_in[5];
    const float* Wih0 = (const float*)d_in[6];
    const float* Whh0 = (const float*)d_in[7];
    const float* bih0 = (const float*)d_in[8];
    const float* bhh0 = (const float*)d_in[9];
    const float* Wih1 = (const float*)d_in[10];
    const float* Whh1 = (const float*)d_in[11];
    const float* bih1 = (const float*)d_in[12];
    const float* bhh1 = (const float*)d_in[13];
    const float* W1   = (const float*)d_in[14];
    const float* b1   = (const float*)d_in[15];
    const float* W2   = (const float*)d_in[16];
    const float* b2   = (const float*)d_in[17];
    float* out = (float*)d_out;
    float* ws  = (float*)d_ws;

    (void)hipMemsetAsync(out + OUT_LOGITS_WORDS, 0, (size_t)OUT_TAIL_WORDS * 4, stream);

    k_wcomb<<<2048, 256, 0, stream>>>(Wih0, Wp, bp, bih0, bhh0, ws);
    k_embg<<<88, 256, 0, stream>>>(emb, Wih0, ws);
    k_zero<<<(ZERO_WORDS + 255) / 256, 256, 0, stream>>>(ws);

    MP p{ mainf, phys, Whh0, Wih1, Whh1, bih1, bhh1, W1, b1, W2, b2, ws, out };
    k_main<<<NWG, NTH, 0, stream>>>(p);
}